// Round 1
// 2150.516 us; speedup vs baseline: 1.6341x; 1.6341x over previous
//
#include <hip/hip_runtime.h>
#include <hip/hip_fp16.h>
#include <cmath>

#define HD 1024
#define OD 8192
#define BD 256
#define TD 64

typedef _Float16 h16;
typedef __attribute__((ext_vector_type(8))) _Float16 half8;
typedef __attribute__((ext_vector_type(4))) float floatx4;

__device__ __forceinline__ void async_cp16(const void* g, void* l) {
  __builtin_amdgcn_global_load_lds((const __attribute__((address_space(1))) void*)g,
                                   (__attribute__((address_space(3))) void*)l,
                                   16, 0, 0);
}

#define WAITVM(N) asm volatile("s_waitcnt vmcnt(" #N ")" ::: "memory")

// ---------------- fc GEMM: C = A[M,K] @ B[N,K]^T + bias, fp16 in, fp32 out -------------
// LDS: 16B chunks, slot(row,j8) holds k8 = j8 ^ (row&7)  (XOR swizzle: coalesced
// global_load_lds AND conflict-free ds_read_b128).
__launch_bounds__(256)
__global__ void gemm_fc(const h16* __restrict__ A, int lda,
                        const h16* __restrict__ B, int ldb,
                        const float* __restrict__ bias, int K,
                        float* __restrict__ out, int ldo) {
  constexpr int BM = 128, BN = 128;
  __shared__ h16 As[BM * 64];
  __shared__ h16 Bs[BN * 64];

  const int tid = threadIdx.x;
  const int lane = tid & 63;
  const int wave = tid >> 6;
  const int wm = wave & 1, wn = wave >> 1;  // 2x2 waves of 64x64
  const int m0 = blockIdx.y * BM;
  const int n0 = blockIdx.x * BN;

  floatx4 acc[4][4] = {};
  const int fr = lane & 15;
  const int kq = lane >> 4;

  for (int k0 = 0; k0 < K; k0 += 64) {
#pragma unroll
    for (int i = 0; i < 4; ++i) {
      int c = tid + i * 256;
      int row = c >> 3, j8 = c & 7;
      int k8 = j8 ^ (row & 7);
      async_cp16(A + (size_t)(m0 + row) * lda + k0 + k8 * 8, &As[c * 8]);
    }
#pragma unroll
    for (int i = 0; i < 4; ++i) {
      int c = tid + i * 256;
      int row = c >> 3, j8 = c & 7;
      int k8 = j8 ^ (row & 7);
      async_cp16(B + (size_t)(n0 + row) * ldb + k0 + k8 * 8, &Bs[c * 8]);
    }
    __syncthreads();

#pragma unroll
    for (int kk = 0; kk < 2; ++kk) {
      half8 af[4], bf[4];
      int k8g = kk * 4 + kq;
#pragma unroll
      for (int mi = 0; mi < 4; ++mi) {
        int row = wm * 64 + mi * 16 + fr;
        af[mi] = *(const half8*)&As[(row * 8 + (k8g ^ (row & 7))) * 8];
      }
#pragma unroll
      for (int ni = 0; ni < 4; ++ni) {
        int row = wn * 64 + ni * 16 + fr;
        bf[ni] = *(const half8*)&Bs[(row * 8 + (k8g ^ (row & 7))) * 8];
      }
#pragma unroll
      for (int mi = 0; mi < 4; ++mi)
#pragma unroll
        for (int ni = 0; ni < 4; ++ni)
          acc[mi][ni] = __builtin_amdgcn_mfma_f32_16x16x32_f16(af[mi], bf[ni], acc[mi][ni], 0, 0, 0);
    }
    __syncthreads();
  }

  // C/D layout: col = lane&15, row = (lane>>4)*4 + reg
#pragma unroll
  for (int mi = 0; mi < 4; ++mi)
#pragma unroll
    for (int ni = 0; ni < 4; ++ni) {
      int colg = n0 + wn * 64 + ni * 16 + fr;
      float bv = bias[colg];
#pragma unroll
      for (int i = 0; i < 4; ++i) {
        int rowg = m0 + wm * 64 + mi * 16 + kq * 4 + i;
        out[(size_t)rowg * ldo + colg] = acc[mi][ni][i] + bv;
      }
    }
}

// ---------------- recurrence cell: split-fp16 GEMM + tanh epilogue ----------------
// A: [BD, 4096] rows = batch, cols [0:2048)=hi([x|h]), [2048:4096)=lo.
// Bh/Bl: [1024, 2048] fp16 hi/lo of [W_ih | W_hh] (row = output neuron).
// acc = A_hi.Bh + A_lo.Bh + A_hi.Bl  (fp32 accumulate; lo.lo dropped ~2^-23)
// Epilogue: t = tanh(acc + bias); write hi/lo pairs to d1 (+c1), d2 (+c2); plain hi to d3.
//
// K-loop is a DEPTH-deep software pipeline (T3+T4): raw s_barrier + counted
// vmcnt waits keep (DEPTH-1) staged K-tiles in flight across barriers instead
// of draining vmcnt(0) every step (the 1-wave/SIMD latency killer).
__launch_bounds__(256)
__global__ void cell_gemm(const h16* __restrict__ A,
                          const h16* __restrict__ Bh, const h16* __restrict__ Bl,
                          const float* __restrict__ bias,
                          h16* __restrict__ d1, int c1,
                          h16* __restrict__ d2, int c2,
                          h16* __restrict__ d3) {
  constexpr int DEPTH = 6;                 // 6 x 16 KiB = 96 KiB LDS, 1 block/CU
  __shared__ h16 smem[DEPTH][4][32 * 64];  // [buf][Ah,Al,Bh,Bl][32x64 tile]

  const int tid = threadIdx.x;
  const int lane = tid & 63;
  const int wave = tid >> 6;
  const int wm = wave & 1, wn = wave >> 1;  // 2x2 waves of 16x16
  const int m0 = blockIdx.y * 32;
  const int n0 = blockIdx.x * 32;

  floatx4 acc = {};
  const int fr = lane & 15;
  const int kq = lane >> 4;

  const int c = tid;           // 256 chunks per 32x64 tile, one per thread
  const int row = c >> 3, j8 = c & 7;
  const int k8 = j8 ^ (row & 7);
  const h16* a_hi = A + (size_t)(m0 + row) * 4096 + k8 * 8;
  const h16* a_lo = a_hi + 2048;
  const h16* b_hi = Bh + (size_t)(n0 + row) * 2048 + k8 * 8;
  const h16* b_lo = Bl + (size_t)(n0 + row) * 2048 + k8 * 8;

  auto stage = [&](int buf, int k0) {
    async_cp16(a_hi + k0, &smem[buf][0][c * 8]);
    async_cp16(a_lo + k0, &smem[buf][1][c * 8]);
    async_cp16(b_hi + k0, &smem[buf][2][c * 8]);
    async_cp16(b_lo + k0, &smem[buf][3][c * 8]);
  };

  const int ra = wm * 16 + fr;
  const int rb = wn * 16 + fr;
  auto compute = [&](int buf) {
#pragma unroll
    for (int kk = 0; kk < 2; ++kk) {
      int k8g = kk * 4 + kq;
      int sa = (ra * 8 + (k8g ^ (ra & 7))) * 8;
      int sb = (rb * 8 + (k8g ^ (rb & 7))) * 8;
      half8 ah = *(const half8*)&smem[buf][0][sa];
      half8 al = *(const half8*)&smem[buf][1][sa];
      half8 bh = *(const half8*)&smem[buf][2][sb];
      half8 bl = *(const half8*)&smem[buf][3][sb];
      acc = __builtin_amdgcn_mfma_f32_16x16x32_f16(ah, bh, acc, 0, 0, 0);
      acc = __builtin_amdgcn_mfma_f32_16x16x32_f16(al, bh, acc, 0, 0, 0);
      acc = __builtin_amdgcn_mfma_f32_16x16x32_f16(ah, bl, acc, 0, 0, 0);
    }
  };

  // prologue: fill the pipe. 4 VMEM instr / stage -> 24 outstanding per wave.
#pragma unroll
  for (int s = 0; s < DEPTH; ++s) stage(s, s * 64);

  // steady state: K = 2048 -> 32 steps; iterate 32-DEPTH with stage(k+DEPTH).
  // wait vmcnt(4*(DEPTH-1)) = oldest tile's 4 loads landed, 5 tiles in flight.
  int buf = 0;
  for (int k = 0; k < 32 - DEPTH; ++k) {
    WAITVM(20);                        // my tile-k loads done
    __builtin_amdgcn_s_barrier();      // everyone's tile-k loads done
    compute(buf);
    __builtin_amdgcn_s_barrier();      // all waves done reading buf -> reusable
    stage(buf, (k + DEPTH) * 64);
    buf = (buf + 1 == DEPTH) ? 0 : buf + 1;
  }
  // drain tail: outstanding shrinks by 4 each step -> exact waits.
#define CELL_TAIL(N)                 \
  WAITVM(N);                         \
  __builtin_amdgcn_s_barrier();      \
  compute(buf);                      \
  buf = (buf + 1 == DEPTH) ? 0 : buf + 1;
  CELL_TAIL(20)
  CELL_TAIL(16)
  CELL_TAIL(12)
  CELL_TAIL(8)
  CELL_TAIL(4)
  CELL_TAIL(0)
#undef CELL_TAIL

  const int colg = n0 + wn * 16 + fr;
  const float bv = bias[colg];
#pragma unroll
  for (int i = 0; i < 4; ++i) {
    int rowg = m0 + wm * 16 + kq * 4 + i;
    float t = tanhf(acc[i] + bv);
    h16 hi = (h16)t;
    h16 lo = (h16)(t - (float)hi);
    size_t r4 = (size_t)rowg * 4096;
    d1[r4 + c1 + colg] = hi;
    d1[r4 + 2048 + c1 + colg] = lo;
    d2[r4 + c2 + colg] = hi;
    d2[r4 + 2048 + c2 + colg] = lo;
    if (d3) d3[(size_t)rowg * HD + colg] = hi;
  }
}

// ---------------- prep kernels ----------------
// Split-pack one layer: Wh/Wl [1024, 2048] = hi/lo of [W_ih | W_hh]
__global__ void pack_split_w(const float* __restrict__ Wih, const float* __restrict__ Whh,
                             h16* __restrict__ Wh, h16* __restrict__ Wl) {
  int idx = blockIdx.x * 256 + threadIdx.x;  // 1024*2048
  int n = idx >> 11, k = idx & 2047;
  float v = (k < HD) ? Wih[n * HD + k] : Whh[n * HD + (k - HD)];
  h16 hi = (h16)v;
  Wh[idx] = hi;
  Wl[idx] = (h16)(v - (float)hi);
}

__global__ void cvt_fp16_4(const float* __restrict__ src, h16* __restrict__ dst, int n4) {
  int i = blockIdx.x * 256 + threadIdx.x;
  if (i < n4) {
    float4 v = ((const float4*)src)[i];
    union { h16 h[4]; unsigned long long u; } o;
    o.h[0] = (h16)v.x; o.h[1] = (h16)v.y; o.h[2] = (h16)v.z; o.h[3] = (h16)v.w;
    ((unsigned long long*)dst)[i] = o.u;
  }
}

__global__ void bias_sum(const float* __restrict__ bih, const float* __restrict__ bhh,
                         float* __restrict__ bsum) {
  int i = blockIdx.x * 256 + threadIdx.x;  // 2048 = [L,H] flat
  bsum[i] = bih[i] + bhh[i];
}

// A0[p=0] = split([x | hidden0]); A1[p=0] h1-slot (+1024) = split(hidden1)
__global__ void init_states(const float* __restrict__ x, const float* __restrict__ hidden,
                            h16* __restrict__ A0, h16* __restrict__ A1) {
  int idx = blockIdx.x * 256 + threadIdx.x;  // 256*2048 + 256*1024
  if (idx < BD * 2048) {
    int b = idx >> 11, k = idx & 2047;
    float v = (k < HD) ? x[b * HD + k] : hidden[b * HD + (k - HD)];
    h16 hi = (h16)v;
    A0[(size_t)b * 4096 + k] = hi;
    A0[(size_t)b * 4096 + 2048 + k] = (h16)(v - (float)hi);
  } else {
    int r = idx - BD * 2048;
    int b = r >> 10, k = r & 1023;
    float v = hidden[BD * HD + b * HD + k];
    h16 hi = (h16)v;
    A1[(size_t)b * 4096 + 1024 + k] = hi;
    A1[(size_t)b * 4096 + 2048 + 1024 + k] = (h16)(v - (float)hi);
  }
}

extern "C" void kernel_launch(void* const* d_in, const int* in_sizes, int n_in,
                              void* d_out, int out_size, void* d_ws, size_t ws_size,
                              hipStream_t stream) {
  const float* x      = (const float*)d_in[0];
  const float* hidden = (const float*)d_in[1];
  // d_in[2] = embedded: only sets T, unused
  const float* W_ih = (const float*)d_in[3];
  const float* W_hh = (const float*)d_in[4];
  const float* b_ih = (const float*)d_in[5];
  const float* b_hh = (const float*)d_in[6];
  const float* fc_W = (const float*)d_in[7];
  const float* fc_b = (const float*)d_in[8];
  float* out = (float*)d_out;

  char* ws = (char*)d_ws;
  size_t off = 0;
  auto alloc = [&](size_t bytes) {
    void* p = ws + off;
    off += (bytes + 255) & ~(size_t)255;
    return p;
  };
  h16* W0h  = (h16*)alloc((size_t)HD * 2048 * 2);
  h16* W0l  = (h16*)alloc((size_t)HD * 2048 * 2);
  h16* W1h  = (h16*)alloc((size_t)HD * 2048 * 2);
  h16* W1l  = (h16*)alloc((size_t)HD * 2048 * 2);
  h16* fcWh = (h16*)alloc((size_t)OD * HD * 2);
  float* bsum = (float*)alloc(2 * HD * 4);
  h16* A0   = (h16*)alloc(2 * (size_t)BD * 4096 * 2);  // [parity][B][4096]=[x_hi|h0_hi|x_lo|h0_lo]
  h16* A1   = (h16*)alloc(2 * (size_t)BD * 4096 * 2);  // [parity][B][4096]=[h0_hi|h1_hi|h0_lo|h1_lo]
  h16* h1all = (h16*)alloc((size_t)TD * BD * HD * 2);  // fc input (hi only)

  pack_split_w<<<8192, 256, 0, stream>>>(W_ih, W_hh, W0h, W0l);
  pack_split_w<<<8192, 256, 0, stream>>>(W_ih + HD * HD, W_hh + HD * HD, W1h, W1l);
  cvt_fp16_4<<<OD * HD / 4 / 256, 256, 0, stream>>>(fc_W, fcWh, OD * HD / 4);
  bias_sum<<<8, 256, 0, stream>>>(b_ih, b_hh, bsum);
  init_states<<<3072, 256, 0, stream>>>(x, hidden, A0, A1);

  dim3 gR(HD / 32, BD / 32);  // (32, 8) = 256 blocks
  for (int t = 0; t < TD; ++t) {
    int p = t & 1, q = p ^ 1;
    h16* A0p = A0 + (size_t)p * BD * 4096;
    h16* A0q = A0 + (size_t)q * BD * 4096;
    h16* A1p = A1 + (size_t)p * BD * 4096;
    h16* A1q = A1 + (size_t)q * BD * 4096;
    // layer 0: h0' = tanh([x|h0]@W0^T + b0) -> A1p slot 0 (h0_out), A0q slot 1024 (next h0)
    cell_gemm<<<gR, 256, 0, stream>>>(A0p, W0h, W0l, bsum,
                                      A1p, 0, A0q + 1024, 0, nullptr);
    // layer 1: h1' -> A0q slot 0 (next x), A1q slot 1024 (next h1), h1all[t]
    cell_gemm<<<gR, 256, 0, stream>>>(A1p, W1h, W1l, bsum + HD,
                                      A0q, 0, A1q + 1024, 0, h1all + (size_t)t * BD * HD);
  }

  // fc: logits[T*B, O] = h1all @ fcW^T + fc_b
  dim3 gF(OD / 128, TD * BD / 128);  // (64, 128) = 8192 blocks
  gemm_fc<<<gF, 256, 0, stream>>>(h1all, HD, fcWh, HD, fc_b, HD, out, OD);
}

// Round 2
// 2009.270 us; speedup vs baseline: 1.7490x; 1.0703x over previous
//
#include <hip/hip_runtime.h>
#include <hip/hip_fp16.h>
#include <cmath>

#define HD 1024
#define OD 8192
#define BD 256
#define TD 64

typedef _Float16 h16;
typedef __attribute__((ext_vector_type(8))) _Float16 half8;
typedef __attribute__((ext_vector_type(4))) float floatx4;

__device__ __forceinline__ void async_cp16(const void* g, void* l) {
  __builtin_amdgcn_global_load_lds((const __attribute__((address_space(1))) void*)g,
                                   (__attribute__((address_space(3))) void*)l,
                                   16, 0, 0);
}

#define WAITVM(N) asm volatile("s_waitcnt vmcnt(" #N ")" ::: "memory")

// ---------------- fc GEMM: C = A[M,K] @ B[N,K]^T + bias, fp16 in, fp32 out -------------
// LDS: 16B chunks, slot(row,j8) holds k8 = j8 ^ (row&7)  (XOR swizzle: coalesced
// global_load_lds AND conflict-free ds_read_b128).
// DEPTH-2 counted-vmcnt pipeline (T3+T4): raw s_barrier + vmcnt(8) keeps one
// 8-load tile in flight across barriers; 64 KB LDS -> 2 blocks/CU for overlap.
__launch_bounds__(256, 2)
__global__ void gemm_fc(const h16* __restrict__ A, int lda,
                        const h16* __restrict__ B, int ldb,
                        const float* __restrict__ bias, int K,
                        float* __restrict__ out, int ldo) {
  constexpr int BM = 128, BN = 128;
  __shared__ h16 As[2][BM * 64];
  __shared__ h16 Bs[2][BN * 64];

  const int tid = threadIdx.x;
  const int lane = tid & 63;
  const int wave = tid >> 6;
  const int wm = wave & 1, wn = wave >> 1;  // 2x2 waves of 64x64
  const int m0 = blockIdx.y * BM;
  const int n0 = blockIdx.x * BN;

  floatx4 acc[4][4] = {};
  const int fr = lane & 15;
  const int kq = lane >> 4;

  auto stage = [&](int buf, int k0) {
#pragma unroll
    for (int i = 0; i < 4; ++i) {
      int c = tid + i * 256;
      int row = c >> 3, j8 = c & 7;
      int k8 = j8 ^ (row & 7);
      async_cp16(A + (size_t)(m0 + row) * lda + k0 + k8 * 8, &As[buf][c * 8]);
    }
#pragma unroll
    for (int i = 0; i < 4; ++i) {
      int c = tid + i * 256;
      int row = c >> 3, j8 = c & 7;
      int k8 = j8 ^ (row & 7);
      async_cp16(B + (size_t)(n0 + row) * ldb + k0 + k8 * 8, &Bs[buf][c * 8]);
    }
  };

  auto compute = [&](int buf) {
#pragma unroll
    for (int kk = 0; kk < 2; ++kk) {
      half8 af[4], bf[4];
      int k8g = kk * 4 + kq;
#pragma unroll
      for (int mi = 0; mi < 4; ++mi) {
        int row = wm * 64 + mi * 16 + fr;
        af[mi] = *(const half8*)&As[buf][(row * 8 + (k8g ^ (row & 7))) * 8];
      }
#pragma unroll
      for (int ni = 0; ni < 4; ++ni) {
        int row = wn * 64 + ni * 16 + fr;
        bf[ni] = *(const half8*)&Bs[buf][(row * 8 + (k8g ^ (row & 7))) * 8];
      }
#pragma unroll
      for (int mi = 0; mi < 4; ++mi)
#pragma unroll
        for (int ni = 0; ni < 4; ++ni)
          acc[mi][ni] = __builtin_amdgcn_mfma_f32_16x16x32_f16(af[mi], bf[ni], acc[mi][ni], 0, 0, 0);
    }
  };

  const int steps = K >> 6;  // 16 for K=1024
  stage(0, 0);
  stage(1, 64);
  int buf = 0;
  for (int k = 0; k < steps - 2; ++k) {
    WAITVM(8);                        // my tile-k loads done (8 in flight for k+1)
    __builtin_amdgcn_s_barrier();     // everyone's tile-k loads done
    compute(buf);
    __builtin_amdgcn_s_barrier();     // buf reusable
    stage(buf, (k + 2) * 64);
    buf ^= 1;
  }
  WAITVM(8);
  __builtin_amdgcn_s_barrier();
  compute(buf);
  buf ^= 1;
  WAITVM(0);
  __builtin_amdgcn_s_barrier();
  compute(buf);

  // C/D layout: col = lane&15, row = (lane>>4)*4 + reg
#pragma unroll
  for (int mi = 0; mi < 4; ++mi)
#pragma unroll
    for (int ni = 0; ni < 4; ++ni) {
      int colg = n0 + wn * 64 + ni * 16 + fr;
      float bv = bias[colg];
#pragma unroll
      for (int i = 0; i < 4; ++i) {
        int rowg = m0 + wm * 64 + mi * 16 + kq * 4 + i;
        out[(size_t)rowg * ldo + colg] = acc[mi][ni][i] + bv;
      }
    }
}

// ---------------- recurrence cell: split-fp16 GEMM + tanh epilogue ----------------
// A: [BD, 4096] rows = batch, cols [0:2048)=hi([x|h]), [2048:4096)=lo.
// Bh/Bl: [1024, 2048] fp16 hi/lo of [W_ih | W_hh] (row = output neuron).
// acc = A_hi.Bh + A_lo.Bh + A_hi.Bl  (fp32 accumulate; lo.lo dropped ~2^-23)
// Epilogue: t = tanh(acc + bias); write hi/lo pairs to d1 (+c1), d2 (+c2); plain hi to d3.
//
// v2: 8 waves, K split across two 4-wave groups (each K=1024, 16 steps) ->
// 2 waves/SIMD for latency overlap, half the barriers per wave. DEPTH=4
// counted-vmcnt pipeline (128 KB LDS, 1 block/CU). Partials combined via LDS.
__launch_bounds__(512)
__global__ void cell_gemm(const h16* __restrict__ A,
                          const h16* __restrict__ Bh, const h16* __restrict__ Bl,
                          const float* __restrict__ bias,
                          h16* __restrict__ d1, int c1,
                          h16* __restrict__ d2, int c2,
                          h16* __restrict__ d3) {
  constexpr int DEPTH = 4;
  __shared__ h16 smem[DEPTH][2][4][32 * 64];  // [buf][kgroup][Ah,Al,Bh,Bl][32x64 tile]

  const int tid = threadIdx.x;
  const int lane = tid & 63;
  const int wave = tid >> 6;          // 0..7
  const int kg = wave >> 2;           // k-group: waves 0-3 -> K[0,1024), 4-7 -> K[1024,2048)
  const int wsub = wave & 3;
  const int wm = wsub & 1, wn = wsub >> 1;  // 2x2 waves of 16x16 per group
  const int m0 = blockIdx.y * 32;
  const int n0 = blockIdx.x * 32;

  floatx4 acc = {};
  const int fr = lane & 15;
  const int kq = lane >> 4;

  // staging: threads 0-255 stage group 0's 4 tiles, 256-511 group 1's.
  // (tid>>8 == wave>>2 == kg, so each wave's vmcnt tracks its own group's tiles)
  const int cc = tid & 255;
  const int row = cc >> 3, j8 = cc & 7;
  const int k8 = j8 ^ (row & 7);
  const size_t kbase = (size_t)kg * 1024;
  const h16* a_hi = A + (size_t)(m0 + row) * 4096 + kbase + k8 * 8;
  const h16* a_lo = a_hi + 2048;
  const h16* b_hi = Bh + (size_t)(n0 + row) * 2048 + kbase + k8 * 8;
  const h16* b_lo = Bl + (size_t)(n0 + row) * 2048 + kbase + k8 * 8;

  auto stage = [&](int buf, int k0) {
    async_cp16(a_hi + k0, &smem[buf][kg][0][cc * 8]);
    async_cp16(a_lo + k0, &smem[buf][kg][1][cc * 8]);
    async_cp16(b_hi + k0, &smem[buf][kg][2][cc * 8]);
    async_cp16(b_lo + k0, &smem[buf][kg][3][cc * 8]);
  };

  const int ra = wm * 16 + fr;
  const int rb = wn * 16 + fr;
  auto compute = [&](int buf) {
#pragma unroll
    for (int kk = 0; kk < 2; ++kk) {
      int k8g = kk * 4 + kq;
      int sa = (ra * 8 + (k8g ^ (ra & 7))) * 8;
      int sb = (rb * 8 + (k8g ^ (rb & 7))) * 8;
      half8 ah = *(const half8*)&smem[buf][kg][0][sa];
      half8 al = *(const half8*)&smem[buf][kg][1][sa];
      half8 bh = *(const half8*)&smem[buf][kg][2][sb];
      half8 bl = *(const half8*)&smem[buf][kg][3][sb];
      acc = __builtin_amdgcn_mfma_f32_16x16x32_f16(ah, bh, acc, 0, 0, 0);
      acc = __builtin_amdgcn_mfma_f32_16x16x32_f16(al, bh, acc, 0, 0, 0);
      acc = __builtin_amdgcn_mfma_f32_16x16x32_f16(ah, bl, acc, 0, 0, 0);
    }
  };

  // prologue: fill the pipe. 4 VMEM instr / stage -> 16 outstanding per wave.
#pragma unroll
  for (int s = 0; s < DEPTH; ++s) stage(s, s * 64);

  // steady state: 16 steps per group; iterate 16-DEPTH with stage(k+DEPTH).
  // wait vmcnt(4*(DEPTH-1)) = my tile-k loads landed, 3 tiles in flight.
  int buf = 0;
  for (int k = 0; k < 16 - DEPTH; ++k) {
    WAITVM(12);                        // my tile-k loads done
    __builtin_amdgcn_s_barrier();      // everyone's tile-k loads done
    compute(buf);
    __builtin_amdgcn_s_barrier();      // all waves done reading buf -> reusable
    stage(buf, (k + DEPTH) * 64);
    buf = (buf + 1) & (DEPTH - 1);
  }
  // drain tail: outstanding shrinks by 4 each step -> exact waits.
#define CELL_TAIL(N)                 \
  WAITVM(N);                         \
  __builtin_amdgcn_s_barrier();      \
  compute(buf);                      \
  buf = (buf + 1) & (DEPTH - 1);
  CELL_TAIL(12)
  CELL_TAIL(8)
  CELL_TAIL(4)
  CELL_TAIL(0)
#undef CELL_TAIL

  // combine group partial sums via LDS, then epilogue by group 0.
  __syncthreads();
  float* fsm = (float*)&smem[0][0][0][0];
  if (kg == 1) {
    *(floatx4*)&fsm[(wsub * 64 + lane) * 4] = acc;
  }
  __syncthreads();
  if (kg == 0) {
    floatx4 other = *(const floatx4*)&fsm[(wsub * 64 + lane) * 4];
    acc += other;
    const int colg = n0 + wn * 16 + fr;
    const float bv = bias[colg];
#pragma unroll
    for (int i = 0; i < 4; ++i) {
      int rowg = m0 + wm * 16 + kq * 4 + i;
      float t = tanhf(acc[i] + bv);
      h16 hi = (h16)t;
      h16 lo = (h16)(t - (float)hi);
      size_t r4 = (size_t)rowg * 4096;
      d1[r4 + c1 + colg] = hi;
      d1[r4 + 2048 + c1 + colg] = lo;
      d2[r4 + c2 + colg] = hi;
      d2[r4 + 2048 + c2 + colg] = lo;
      if (d3) d3[(size_t)rowg * HD + colg] = hi;
    }
  }
}

// ---------------- prep kernels ----------------
// Split-pack one layer: Wh/Wl [1024, 2048] = hi/lo of [W_ih | W_hh]
__global__ void pack_split_w(const float* __restrict__ Wih, const float* __restrict__ Whh,
                             h16* __restrict__ Wh, h16* __restrict__ Wl) {
  int idx = blockIdx.x * 256 + threadIdx.x;  // 1024*2048
  int n = idx >> 11, k = idx & 2047;
  float v = (k < HD) ? Wih[n * HD + k] : Whh[n * HD + (k - HD)];
  h16 hi = (h16)v;
  Wh[idx] = hi;
  Wl[idx] = (h16)(v - (float)hi);
}

__global__ void cvt_fp16_4(const float* __restrict__ src, h16* __restrict__ dst, int n4) {
  int i = blockIdx.x * 256 + threadIdx.x;
  if (i < n4) {
    float4 v = ((const float4*)src)[i];
    union { h16 h[4]; unsigned long long u; } o;
    o.h[0] = (h16)v.x; o.h[1] = (h16)v.y; o.h[2] = (h16)v.z; o.h[3] = (h16)v.w;
    ((unsigned long long*)dst)[i] = o.u;
  }
}

__global__ void bias_sum(const float* __restrict__ bih, const float* __restrict__ bhh,
                         float* __restrict__ bsum) {
  int i = blockIdx.x * 256 + threadIdx.x;  // 2048 = [L,H] flat
  bsum[i] = bih[i] + bhh[i];
}

// A0[p=0] = split([x | hidden0]); A1[p=0] h1-slot (+1024) = split(hidden1)
__global__ void init_states(const float* __restrict__ x, const float* __restrict__ hidden,
                            h16* __restrict__ A0, h16* __restrict__ A1) {
  int idx = blockIdx.x * 256 + threadIdx.x;  // 256*2048 + 256*1024
  if (idx < BD * 2048) {
    int b = idx >> 11, k = idx & 2047;
    float v = (k < HD) ? x[b * HD + k] : hidden[b * HD + (k - HD)];
    h16 hi = (h16)v;
    A0[(size_t)b * 4096 + k] = hi;
    A0[(size_t)b * 4096 + 2048 + k] = (h16)(v - (float)hi);
  } else {
    int r = idx - BD * 2048;
    int b = r >> 10, k = r & 1023;
    float v = hidden[BD * HD + b * HD + k];
    h16 hi = (h16)v;
    A1[(size_t)b * 4096 + 1024 + k] = hi;
    A1[(size_t)b * 4096 + 2048 + 1024 + k] = (h16)(v - (float)hi);
  }
}

extern "C" void kernel_launch(void* const* d_in, const int* in_sizes, int n_in,
                              void* d_out, int out_size, void* d_ws, size_t ws_size,
                              hipStream_t stream) {
  const float* x      = (const float*)d_in[0];
  const float* hidden = (const float*)d_in[1];
  // d_in[2] = embedded: only sets T, unused
  const float* W_ih = (const float*)d_in[3];
  const float* W_hh = (const float*)d_in[4];
  const float* b_ih = (const float*)d_in[5];
  const float* b_hh = (const float*)d_in[6];
  const float* fc_W = (const float*)d_in[7];
  const float* fc_b = (const float*)d_in[8];
  float* out = (float*)d_out;

  char* ws = (char*)d_ws;
  size_t off = 0;
  auto alloc = [&](size_t bytes) {
    void* p = ws + off;
    off += (bytes + 255) & ~(size_t)255;
    return p;
  };
  h16* W0h  = (h16*)alloc((size_t)HD * 2048 * 2);
  h16* W0l  = (h16*)alloc((size_t)HD * 2048 * 2);
  h16* W1h  = (h16*)alloc((size_t)HD * 2048 * 2);
  h16* W1l  = (h16*)alloc((size_t)HD * 2048 * 2);
  h16* fcWh = (h16*)alloc((size_t)OD * HD * 2);
  float* bsum = (float*)alloc(2 * HD * 4);
  h16* A0   = (h16*)alloc(2 * (size_t)BD * 4096 * 2);  // [parity][B][4096]=[x_hi|h0_hi|x_lo|h0_lo]
  h16* A1   = (h16*)alloc(2 * (size_t)BD * 4096 * 2);  // [parity][B][4096]=[h0_hi|h1_hi|h0_lo|h1_lo]
  h16* h1all = (h16*)alloc((size_t)TD * BD * HD * 2);  // fc input (hi only)

  pack_split_w<<<8192, 256, 0, stream>>>(W_ih, W_hh, W0h, W0l);
  pack_split_w<<<8192, 256, 0, stream>>>(W_ih + HD * HD, W_hh + HD * HD, W1h, W1l);
  cvt_fp16_4<<<OD * HD / 4 / 256, 256, 0, stream>>>(fc_W, fcWh, OD * HD / 4);
  bias_sum<<<8, 256, 0, stream>>>(b_ih, b_hh, bsum);
  init_states<<<3072, 256, 0, stream>>>(x, hidden, A0, A1);

  dim3 gR(HD / 32, BD / 32);  // (32, 8) = 256 blocks
  for (int t = 0; t < TD; ++t) {
    int p = t & 1, q = p ^ 1;
    h16* A0p = A0 + (size_t)p * BD * 4096;
    h16* A0q = A0 + (size_t)q * BD * 4096;
    h16* A1p = A1 + (size_t)p * BD * 4096;
    h16* A1q = A1 + (size_t)q * BD * 4096;
    // layer 0: h0' = tanh([x|h0]@W0^T + b0) -> A1p slot 0 (h0_out), A0q slot 1024 (next h0)
    cell_gemm<<<gR, 512, 0, stream>>>(A0p, W0h, W0l, bsum,
                                      A1p, 0, A0q + 1024, 0, nullptr);
    // layer 1: h1' -> A0q slot 0 (next x), A1q slot 1024 (next h1), h1all[t]
    cell_gemm<<<gR, 512, 0, stream>>>(A1p, W1h, W1l, bsum + HD,
                                      A0q, 0, A1q + 1024, 0, h1all + (size_t)t * BD * HD);
  }

  // fc: logits[T*B, O] = h1all @ fcW^T + fc_b
  dim3 gF(OD / 128, TD * BD / 128);  // (64, 128) = 8192 blocks
  gemm_fc<<<gF, 256, 0, stream>>>(h1all, HD, fcWh, HD, fc_b, HD, out, OD);
}